// Round 3
// baseline (190.985 us; speedup 1.0000x reference)
//
#include <hip/hip_runtime.h>

#define NE 62
#define NTRIL 1953
// Chunk-major symmetric-A layout (conflict-free per-lane 16B reads in props):
//   ch<15 : Ac[ch*248 + j*4 + k] = A[j][4ch+k]
//   tail  : Ac[3720 + j*2 + k]   = A[j][60+k]
#define ATOT 3844

// Single fused kernel: one wave per graph (1024 blocks x 4 waves).
// Per block: build raw A (chunk-major) in LDS from the 1953 tril params,
// compute dinv = rsqrt(rowsum|A|), then per wave run the reference's K=2
// propagation with dinv folded in:
//   Xs'   = dinv[i] * X[i]                       (prescale, per-wave)
//   Y1*[i]= dinv[i]^2 * (A @ Xs')[i]             (prop 1)
//   Y2[j] = dinv[j]   * (A @ Y1*)[j]             (prop 2)  == (An^2 @ X)[j]
// then relu-linear + pool + 3-class head (shfl butterfly).
__global__ __launch_bounds__(256) void fused_fwd(const float* __restrict__ x,
        const float* __restrict__ adj_tril,
        const float* __restrict__ lin_w, const float* __restrict__ lin_b,
        const float* __restrict__ fc_w, const float* __restrict__ fc_b,
        float* __restrict__ out) {
    __shared__ float Ac[ATOT];
    __shared__ float dinv[64];
    __shared__ float Xs[4 * 312];        // 310 floats/graph, padded (16B align)
    __shared__ float Y1s[4][NE * 8];     // prop-1 result, broadcast-read in prop 2
    __shared__ float Y2s[4][NE * 12];    // prop-2 result, broadcast-read in pool
    int tid = threadIdx.x;
    int wid = tid >> 6;
    int lane = tid & 63;
    int b = blockIdx.x * 4 + wid;

    // ---- per-lane weights (global, L1/L2-cached; hoisted before barriers) ----
    int c = lane & 31;
    float w0 = lin_w[c * 5 + 0], w1 = lin_w[c * 5 + 1], w2 = lin_w[c * 5 + 2],
          w3 = lin_w[c * 5 + 3], w4 = lin_w[c * 5 + 4];
    float lb = lin_b[c];
    float f0 = fc_w[c], f1 = fc_w[32 + c], f2 = fc_w[64 + c];

    // ---- stage x (coalesced float2) ----
    {
        const float2* xsrc = (const float2*)(x + (size_t)blockIdx.x * 1240);
        for (int t = tid; t < 620; t += 256) {
            int w = t / 155, o = t - w * 155;
            *(float2*)&Xs[w * 312 + o * 2] = xsrc[t];
        }
    }
    // ---- fill chunk-major symmetric A from tril params ----
    for (int addr = tid; addr < ATOT; addr += 256) {
        int i, j;
        if (addr < 3720) {
            int ch = addr / 248, rem = addr - ch * 248;
            j = rem >> 2;
            i = ch * 4 + (rem & 3);
        } else {
            int rem = addr - 3720;
            j = rem >> 1;
            i = 60 + (rem & 1);
        }
        int a = j > i ? j : i, s = j + i - a;        // a=max, s=min
        Ac[addr] = adj_tril[a * (a + 1) / 2 + s];
    }
    __syncthreads();
    // ---- dinv (wave 0, lanes 0..61): conflict-free per-lane contiguous reads ----
    if (tid < NE) {
        float s = 0.f;
#pragma unroll
        for (int ch = 0; ch < 15; ++ch) {
            float4 a = *(const float4*)(Ac + ch * 248 + tid * 4);
            s += fabsf(a.x) + fabsf(a.y) + fabsf(a.z) + fabsf(a.w);
        }
        s += fabsf(Ac[3720 + tid * 2]) + fabsf(Ac[3721 + tid * 2]);
        dinv[tid] = (s > 0.f) ? rsqrtf(s) : 0.f;
    }
    __syncthreads();
    // ---- prescale own wave's X rows by dinv (same-wave; no barrier after) ----
    float* xb = Xs + wid * 312;
    if (lane < NE) {
        float dv = dinv[lane];
        float* xr = xb + lane * 5;
        xr[0] *= dv; xr[1] *= dv; xr[2] *= dv; xr[3] *= dv; xr[4] *= dv;
    }
    // ---- prop 1: lane j: t = A_row_j . Xs' ; store dinv[j]^2 * t ----
    if (lane < NE) {
        float y0 = 0, y1 = 0, y2 = 0, y3 = 0, y4 = 0;
#pragma unroll
        for (int ch = 0; ch < 15; ++ch) {
            float4 m = *(const float4*)(Ac + ch * 248 + lane * 4);   // contiguous/lane
            const float4* xi = (const float4*)(xb + ch * 20);        // wave-uniform bcast
            float4 xa = xi[0], xv = xi[1], xc = xi[2], xd = xi[3], xe = xi[4];
            y0 += m.x * xa.x; y1 += m.x * xa.y; y2 += m.x * xa.z; y3 += m.x * xa.w; y4 += m.x * xv.x;
            y0 += m.y * xv.y; y1 += m.y * xv.z; y2 += m.y * xv.w; y3 += m.y * xc.x; y4 += m.y * xc.y;
            y0 += m.z * xc.z; y1 += m.z * xc.w; y2 += m.z * xd.x; y3 += m.z * xd.y; y4 += m.z * xd.z;
            y0 += m.w * xd.w; y1 += m.w * xe.x; y2 += m.w * xe.y; y3 += m.w * xe.z; y4 += m.w * xe.w;
        }
        float2 mt = *(const float2*)(Ac + 3720 + lane * 2);
        const float* xt = xb + 300;
        y0 += mt.x * xt[0] + mt.y * xt[5];
        y1 += mt.x * xt[1] + mt.y * xt[6];
        y2 += mt.x * xt[2] + mt.y * xt[7];
        y3 += mt.x * xt[3] + mt.y * xt[8];
        y4 += mt.x * xt[4] + mt.y * xt[9];
        float dv = dinv[lane], dv2 = dv * dv;
        float* yr = &Y1s[wid][lane * 8];
        *(float4*)yr = make_float4(y0 * dv2, y1 * dv2, y2 * dv2, y3 * dv2);
        yr[4] = y4 * dv2;
    }
    // ---- prop 2 (same-wave dependency only; no block barrier needed) ----
    if (lane < NE) {
        const float* yb = Y1s[wid];
        float y0 = 0, y1 = 0, y2 = 0, y3 = 0, y4 = 0;
#pragma unroll
        for (int ch = 0; ch < 15; ++ch) {
            float4 m = *(const float4*)(Ac + ch * 248 + lane * 4);
            const float* r0 = yb + (4 * ch) * 8;                     // bcast rows
            float4 a0 = *(const float4*)(r0);      float e0 = r0[4];
            float4 a1 = *(const float4*)(r0 + 8);  float e1 = r0[12];
            float4 a2 = *(const float4*)(r0 + 16); float e2 = r0[20];
            float4 a3 = *(const float4*)(r0 + 24); float e3 = r0[28];
            y0 += m.x * a0.x; y1 += m.x * a0.y; y2 += m.x * a0.z; y3 += m.x * a0.w; y4 += m.x * e0;
            y0 += m.y * a1.x; y1 += m.y * a1.y; y2 += m.y * a1.z; y3 += m.y * a1.w; y4 += m.y * e1;
            y0 += m.z * a2.x; y1 += m.z * a2.y; y2 += m.z * a2.z; y3 += m.z * a2.w; y4 += m.z * e2;
            y0 += m.w * a3.x; y1 += m.w * a3.y; y2 += m.w * a3.z; y3 += m.w * a3.w; y4 += m.w * e3;
        }
        float2 mt = *(const float2*)(Ac + 3720 + lane * 2);
        const float* r60 = yb + 60 * 8;
        const float* r61 = yb + 61 * 8;
        y0 += mt.x * r60[0] + mt.y * r61[0];
        y1 += mt.x * r60[1] + mt.y * r61[1];
        y2 += mt.x * r60[2] + mt.y * r61[2];
        y3 += mt.x * r60[3] + mt.y * r61[3];
        y4 += mt.x * r60[4] + mt.y * r61[4];
        float dv = dinv[lane];
        float* yr = &Y2s[wid][lane * 12];
        *(float4*)yr = make_float4(y0 * dv, y1 * dv, y2 * dv, y3 * dv);
        yr[4] = y4 * dv;
    }
    // ---- pool: lane (half,c) accumulates relu(Y2[j].W[c]+b[c]) over its j-half ----
    int half = lane >> 5;
    float acc = 0.f;
    int jbeg = half * 31;
    for (int t = 0; t < 31; ++t) {
        const float* yr = &Y2s[wid][(jbeg + t) * 12];   // same addr across half: bcast
        float4 yv = *(const float4*)yr;
        float d = yv.x * w0 + yv.y * w1 + yv.z * w2 + yv.w * w3 + yr[4] * w4 + lb;
        acc += fmaxf(d, 0.f);
    }
    acc += __shfl_xor(acc, 32, 64);   // combine j-halves; all lanes hold pooled[c]
    // ---- head ----
    float p0 = acc * f0, p1 = acc * f1, p2 = acc * f2;
#pragma unroll
    for (int m = 16; m >= 1; m >>= 1) {
        p0 += __shfl_xor(p0, m, 64);
        p1 += __shfl_xor(p1, m, 64);
        p2 += __shfl_xor(p2, m, 64);
    }
    if (lane == 0) {
        out[b * 3 + 0] = p0 + fc_b[0];
        out[b * 3 + 1] = p1 + fc_b[1];
        out[b * 3 + 2] = p2 + fc_b[2];
    }
}

extern "C" void kernel_launch(void* const* d_in, const int* in_sizes, int n_in,
                              void* d_out, int out_size, void* d_ws, size_t ws_size,
                              hipStream_t stream) {
    const float* x        = (const float*)d_in[0];
    const float* adj_tril = (const float*)d_in[1];
    const float* lin_w    = (const float*)d_in[2];
    const float* lin_b    = (const float*)d_in[3];
    const float* fc_w     = (const float*)d_in[4];
    const float* fc_b     = (const float*)d_in[5];
    // d_in[6]=edge_index, d_in[7]=batch_idx: structurally redundant (dense
    // all-pairs per-graph) — never read. d_ws: unused.
    float* out = (float*)d_out;

    fused_fwd<<<1024, 256, 0, stream>>>(x, adj_tril, lin_w, lin_b, fc_w, fc_b, out);
}

// Round 4
// 183.749 us; speedup vs baseline: 1.0394x; 1.0394x over previous
//
#include <hip/hip_runtime.h>

// REVERT to round-2 structure (best measured: 184.3 µs total).
// Round-3 fusion regressed +6.7 µs: per-block A-rebuild + doubled propagation
// cost more than the build_M launch + M staging it removed. Keep M amortized:
// built once by 16 blocks, consumed by 1024.

#define NE 62
#define IC 5
#define NTRIL 1953
#define SA 68               // internal row stride in build_M's LDS
#define MTOT 3844           // floats in chunk-major M: 15*248 + 124
// Chunk-major M layout: for ch<15: Mc[ch*248 + j*4 + k] = M[j][4ch+k]
//                        tail:     Mc[3720 + j*2 + k]   = M[j][60+k]
// Forward-phase-A lane j then reads contiguous 16B per lane -> conflict-free.

// Kernel 1: M = (D^-1/2 A D^-1/2)^2 from the 1953 lower-tri params.
__global__ __launch_bounds__(256) void build_M(const float* __restrict__ adj_tril,
                                               float* __restrict__ Mg) {
    __shared__ float A[NE * SA];
    __shared__ float dinv[NE];
    int tid = threadIdx.x;
    for (int t = tid; t < NTRIL; t += 256) {
        float v = adj_tril[t];
        float r = sqrtf((float)(8 * t + 1));
        int i = (int)((r - 1.0f) * 0.5f);
        while ((i + 1) * (i + 2) / 2 <= t) ++i;
        while (i * (i + 1) / 2 > t) --i;
        int j = t - i * (i + 1) / 2;
        A[i * SA + j] = v;
        A[j * SA + i] = v;
    }
    __syncthreads();
    if (tid < NE) {
        float s = 0.f;
        for (int k = 0; k < NE; ++k) s += fabsf(A[tid * SA + k]);
        dinv[tid] = (s > 0.f) ? rsqrtf(s) : 0.f;
    }
    __syncthreads();
    for (int g = tid; g < NE * NE; g += 256) {
        int i = g / NE, j = g % NE;
        A[i * SA + j] *= dinv[i] * dinv[j];
    }
    __syncthreads();
    int g = blockIdx.x * 256 + tid;
    if (g < NE * NE) {
        int r = g / NE, cidx = g % NE;   // M[r][cidx] = dot(An row r, An row cidx)
        const float4* ra = (const float4*)(A + r * SA);
        const float4* rb = (const float4*)(A + cidx * SA);
        float acc = 0.f;
#pragma unroll
        for (int c = 0; c < 15; ++c) {
            float4 a = ra[c], b = rb[c];
            acc += a.x * b.x + a.y * b.y + a.z * b.z + a.w * b.w;
        }
        acc += A[r * SA + 60] * A[cidx * SA + 60] + A[r * SA + 61] * A[cidx * SA + 61];
        int addr = (cidx < 60) ? ((cidx >> 2) * 248 + r * 4 + (cidx & 3))
                               : (3720 + r * 2 + (cidx - 60));
        Mg[addr] = acc;
    }
}

// Kernel 2: per-graph forward, one wave per graph (1024 blocks x 4 waves).
__global__ __launch_bounds__(256) void forward_k(const float* __restrict__ x,
        const float* __restrict__ lin_w, const float* __restrict__ lin_b,
        const float* __restrict__ fc_w, const float* __restrict__ fc_b,
        const float* __restrict__ Mg, float* __restrict__ out) {
    __shared__ float Mlds[MTOT];          // chunk-major, conflict-free for phase A
    __shared__ float Xs[4 * 312];         // 310 floats/graph, padded to 312 (16B align)
    __shared__ float Ys[4][NE * 12];      // per-wave Y; phase-B reads are broadcasts
    int tid = threadIdx.x;
    // ---- coalesced staging ----
    {
        const float4* src = (const float4*)Mg;
        float4* dst = (float4*)Mlds;
        for (int t = tid; t < MTOT / 4; t += 256) dst[t] = src[t];
        const float2* xsrc = (const float2*)(x + (size_t)blockIdx.x * (4 * 310));
        for (int t = tid; t < 620; t += 256) {          // 155 float2 per graph
            int w = t / 155, o = t - w * 155;
            *(float2*)&Xs[w * 312 + o * 2] = xsrc[t];
        }
    }
    int wid = tid >> 6;
    int lane = tid & 63;
    int b = blockIdx.x * 4 + wid;
    int c = lane & 31;
    float w0 = lin_w[c * 5 + 0], w1 = lin_w[c * 5 + 1], w2 = lin_w[c * 5 + 2],
          w3 = lin_w[c * 5 + 3], w4 = lin_w[c * 5 + 4];
    float lb = lin_b[c];
    float f0 = fc_w[c], f1 = fc_w[32 + c], f2 = fc_w[64 + c];
    __syncthreads();
    // ---- phase A: lane j computes Y[j,0:5] = sum_i M[j,i] * X[i,0:5] ----
    int j = lane;
    if (j < NE) {
        const float* xb = Xs + wid * 312;
        float y0 = 0, y1 = 0, y2 = 0, y3 = 0, y4 = 0;
#pragma unroll
        for (int ch = 0; ch < 15; ++ch) {
            float4 m = *(const float4*)(Mlds + ch * 248 + j * 4);   // contiguous/lane
            const float4* xi = (const float4*)(xb + ch * 20);       // wave-uniform bcast
            float4 xa = xi[0], xv = xi[1], xc = xi[2], xd = xi[3], xe = xi[4];
            y0 += m.x * xa.x; y1 += m.x * xa.y; y2 += m.x * xa.z; y3 += m.x * xa.w; y4 += m.x * xv.x;
            y0 += m.y * xv.y; y1 += m.y * xv.z; y2 += m.y * xv.w; y3 += m.y * xc.x; y4 += m.y * xc.y;
            y0 += m.z * xc.z; y1 += m.z * xc.w; y2 += m.z * xd.x; y3 += m.z * xd.y; y4 += m.z * xd.z;
            y0 += m.w * xd.w; y1 += m.w * xe.x; y2 += m.w * xe.y; y3 += m.w * xe.z; y4 += m.w * xe.w;
        }
        float2 mt = *(const float2*)(Mlds + 3720 + j * 2);          // 2-way = free
        const float* xt = xb + 300;
        y0 += mt.x * xt[0] + mt.y * xt[5];
        y1 += mt.x * xt[1] + mt.y * xt[6];
        y2 += mt.x * xt[2] + mt.y * xt[7];
        y3 += mt.x * xt[3] + mt.y * xt[8];
        y4 += mt.x * xt[4] + mt.y * xt[9];
        float* yr = &Ys[wid][j * 12];
        *(float4*)yr = make_float4(y0, y1, y2, y3);
        yr[4] = y4;
    }
    __syncthreads();
    // ---- phase B: lane (half,c) accumulates relu(Y[j]·W[c]+b[c]) over its j-half ----
    int half = lane >> 5;
    float acc = 0.f;
    int jbeg = half * 31;
    for (int t = 0; t < 31; ++t) {
        const float* yr = &Ys[wid][(jbeg + t) * 12];   // same addr across half: bcast
        float4 yv = *(const float4*)yr;
        float d = yv.x * w0 + yv.y * w1 + yv.z * w2 + yv.w * w3 + yr[4] * w4 + lb;
        acc += fmaxf(d, 0.f);
    }
    acc += __shfl_xor(acc, 32, 64);   // combine j-halves; all lanes hold pooled[c]
    // ---- head ----
    float p0 = acc * f0, p1 = acc * f1, p2 = acc * f2;
#pragma unroll
    for (int m = 16; m >= 1; m >>= 1) {
        p0 += __shfl_xor(p0, m, 64);
        p1 += __shfl_xor(p1, m, 64);
        p2 += __shfl_xor(p2, m, 64);
    }
    if (lane == 0) {
        out[b * 3 + 0] = p0 + fc_b[0];
        out[b * 3 + 1] = p1 + fc_b[1];
        out[b * 3 + 2] = p2 + fc_b[2];
    }
}

extern "C" void kernel_launch(void* const* d_in, const int* in_sizes, int n_in,
                              void* d_out, int out_size, void* d_ws, size_t ws_size,
                              hipStream_t stream) {
    const float* x        = (const float*)d_in[0];
    const float* adj_tril = (const float*)d_in[1];
    const float* lin_w    = (const float*)d_in[2];
    const float* lin_b    = (const float*)d_in[3];
    const float* fc_w     = (const float*)d_in[4];
    const float* fc_b     = (const float*)d_in[5];
    // d_in[6]=edge_index, d_in[7]=batch_idx: structurally redundant (dense
    // all-pairs per-graph) — never read.
    float* out = (float*)d_out;
    float* Mg  = (float*)d_ws;   // 3844 floats of scratch

    build_M<<<16, 256, 0, stream>>>(adj_tril, Mg);
    forward_k<<<1024, 256, 0, stream>>>(x, lin_w, lin_b, fc_w, fc_b, Mg, out);
}